// Round 4
// baseline (443.344 us; speedup 1.0000x reference)
//
#include <hip/hip_runtime.h>
#include <math.h>

// MHA fwd: B=8 H=16 T=1024 D=1024 dh=64. fp32 in/out, bf16 MFMA compute.
// Split-bf16 (hi+lo) 3-term MFMA for x@Wq, x@Wk and Q@K^T (logits sigma~1024
// need ~fp32 accuracy; 2-term and int8 variants fail the error budget).
// R1: S^T = K.Q^T formulation (softmax in-lane, P = A-frag of 16x16x16 MFMA).
// R2: Q/K/V frag-major panels + XCD swizzle (conflict-free LDS, L2 reuse).
// R3: attn q-tile 256 w/ 512-thr blocks (halve staging+fetch per q-row);
//     V frag layout fused into V-GEMM epilogue (vfrag kernel deleted).

typedef unsigned short u16;
typedef unsigned int u32;
typedef __bf16  bf16x8 __attribute__((ext_vector_type(8)));
typedef unsigned short u16x8 __attribute__((ext_vector_type(8)));
typedef unsigned short u16x4 __attribute__((ext_vector_type(4)));
typedef short s16x4 __attribute__((ext_vector_type(4)));
typedef unsigned int u32x2 __attribute__((ext_vector_type(2)));
typedef float f32x4 __attribute__((ext_vector_type(4)));

#define MFMA16(a,b,c) __builtin_amdgcn_mfma_f32_16x16x32_bf16((a),(b),(c),0,0,0)
#define MFMA16K16(a,b,c) __builtin_amdgcn_mfma_f32_16x16x16bf16_1k((a),(b),(c),0,0,0)

static __device__ __forceinline__ u16 f2b(float f){
  unsigned u = __builtin_bit_cast(unsigned, f);
  u += 0x7fffu + ((u >> 16) & 1u);            // RNE
  return (u16)(u >> 16);
}
static __device__ __forceinline__ float b2f(u16 h){
  unsigned u = ((unsigned)h) << 16;
  return __builtin_bit_cast(float, u);
}
static __device__ __forceinline__ bf16x8 ldsfrag(const u16* p){
  return __builtin_bit_cast(bf16x8, *(const u16x8*)p);
}
static __device__ __forceinline__ u32 packhi(float fa, float fb){
  return __builtin_amdgcn_perm(__builtin_bit_cast(u32, fa),
                               __builtin_bit_cast(u32, fb), 0x07060302u);
}
static __device__ __forceinline__ void gld16(const void* g, void* l){
  __builtin_amdgcn_global_load_lds(
      (const __attribute__((address_space(1))) void*)g,
      (__attribute__((address_space(3))) void*)l, 16, 0, 0);
}

// Frag-major panel conventions (u16 index), bh = b*16+h, tt = t&1023, d in [0,64):
//  K (A-frag of 16x16x32):  ktile=tt>>7 fkt=(tt>>4)&7 l15=tt&15 | kc=d>>5 q=(d>>3)&3 j=d&7
//    idx = (((bh*8+ktile)*8+fkt)*2+kc)*512 + (q*16+l15)*8 + j          [16KB/ktile]
//  Q (B-frag of 16x16x32):  qtile=tt>>7 r=tt&127 wv=r>>5 mt=(r>>4)&1 l15=tt&15
//    idx = ((((bh*8+qtile)*4+wv)*2+mt)*2+kc)*512 + (q*16+l15)*8 + j    [16KB/qtile]
//  V (B-frag of 16x16x16):  ktile=tt>>7 fkt=(tt>>4)&7 q=(tt>>2)&3 j=tt&3 | nd=d>>4 l15=d&15
//    idx = ((((bh*8+ktile)*8+fkt)*4+nd)*64 + q*16+l15)*4 + j           [16KB/ktile]

// ---------------- split x (fp32 -> hi/lo bf16) ----------------
__global__ __launch_bounds__(256) void split_x_kernel(
    const float* __restrict__ x, u16* __restrict__ xh, u16* __restrict__ xl, int n)
{
  int i = (blockIdx.x * 256 + threadIdx.x) * 8;
  if (i >= n) return;
  float4 v0 = *(const float4*)(x + i);
  float4 v1 = *(const float4*)(x + i + 4);
  float vv[8] = {v0.x, v0.y, v0.z, v0.w, v1.x, v1.y, v1.z, v1.w};
  u16x8 hv, lv;
#pragma unroll
  for (int j = 0; j < 8; j++){
    u16 hb = f2b(vv[j]);
    hv[j] = hb;
    lv[j] = f2b(vv[j] - b2f(hb));
  }
  *(u16x8*)(xh + i) = hv;
  *(u16x8*)(xl + i) = lv;
}

// ---------------- transpose W (fp32 KxN -> bf16 NxK, optional lo) ----------------
__global__ __launch_bounds__(256) void transpose_split_kernel(
    const float* __restrict__ W, u16* __restrict__ Th, u16* __restrict__ Tl,
    int KD, int ND)
{
  __shared__ float t[32][33];
  int n0 = blockIdx.x * 32, k0 = blockIdx.y * 32;
  int tx = threadIdx.x, ty = threadIdx.y;
#pragma unroll
  for (int i = 0; i < 4; i++){
    int k = k0 + ty + i * 8;
    t[ty + i * 8][tx] = W[(size_t)k * ND + n0 + tx];
  }
  __syncthreads();
#pragma unroll
  for (int i = 0; i < 4; i++){
    int n = n0 + ty + i * 8;
    float v = t[tx][ty + i * 8];
    u16 h = f2b(v);
    Th[(size_t)n * KD + k0 + tx] = h;
    if (Tl) Tl[(size_t)n * KD + k0 + tx] = f2b(v - b2f(h));
  }
}

// ---------------- plain bf16 GEMM: C = A * Bt^T ----------------
// OUTMODE 0: fp32 row-major C[M][N].  OUTMODE 2: bf16 V-frag panels (N=1024).
template<int OUTMODE>
__global__ __launch_bounds__(256) void gemm_bt_kernel(
    const u16* __restrict__ A, const u16* __restrict__ Bt, void* __restrict__ Cv,
    int M, int N, int K)
{
  __shared__ __attribute__((aligned(16))) u16 lA[4096], lB[4096];
  const int tid = threadIdx.x, lane = tid & 63, wave = tid >> 6;
  const int quad = lane >> 4, l15 = lane & 15;
  const int row0 = blockIdx.x * 128, col0 = blockIdx.y * 128;
  const int wm = wave >> 1, wn = wave & 1;
  const int sr = lane >> 2, sc = (lane & 3) * 8;
  f32x4 acc[4][4];
#pragma unroll
  for (int mt = 0; mt < 4; mt++)
#pragma unroll
    for (int nt = 0; nt < 4; nt++) acc[mt][nt] = (f32x4)0.0f;

  for (int k0 = 0; k0 < K; k0 += 32){
#pragma unroll
    for (int i = 0; i < 2; i++){
      int c = wave * 2 + i;
      gld16(A  + (size_t)(row0 + c * 16 + sr) * K + k0 + sc, &lA[c * 512]);
      gld16(Bt + (size_t)(col0 + c * 16 + sr) * K + k0 + sc, &lB[c * 512]);
    }
    __syncthreads();
    bf16x8 a[4], b[4];
#pragma unroll
    for (int t = 0; t < 4; t++){
      a[t] = ldsfrag(&lA[(wm * 64 + t * 16 + l15) * 32 + quad * 8]);
      b[t] = ldsfrag(&lB[(wn * 64 + t * 16 + l15) * 32 + quad * 8]);
    }
#pragma unroll
    for (int mt = 0; mt < 4; mt++)
#pragma unroll
      for (int nt = 0; nt < 4; nt++)
        acc[mt][nt] = MFMA16(a[mt], b[nt], acc[mt][nt]);
    __syncthreads();
  }
  if (OUTMODE == 2){
    // V-frag epilogue: j = r (contiguous) -> one u16x4 store per (mt,nt)
#pragma unroll
    for (int mt = 0; mt < 4; mt++)
#pragma unroll
      for (int nt = 0; nt < 4; nt++){
        int row = row0 + wm * 64 + mt * 16 + quad * 4;
        int col = col0 + wn * 64 + nt * 16 + l15;
        int bb = row >> 10, tt = row & 1023;
        int hh = (col >> 6) & 15, d = col & 63;
        int bhI = bb * 16 + hh;
        int ktile = tt >> 7, fkt = (tt >> 4) & 7, qF = (tt >> 2) & 3;
        int nd = d >> 4, l15F = d & 15;
        size_t idx = ((((size_t)(bhI * 8 + ktile) * 8 + fkt) * 4 + nd) * 64
                      + qF * 16 + l15F) * 4;
        u16x4 vals;
#pragma unroll
        for (int r = 0; r < 4; r++) vals[r] = f2b(acc[mt][nt][r]);
        *(u16x4*)(((u16*)Cv) + idx) = vals;
      }
  } else {
#pragma unroll
    for (int mt = 0; mt < 4; mt++)
#pragma unroll
      for (int nt = 0; nt < 4; nt++)
#pragma unroll
        for (int r = 0; r < 4; r++){
          int row = row0 + wm * 64 + mt * 16 + quad * 4 + r;
          int col = col0 + wn * 64 + nt * 16 + l15;
          ((float*)Cv)[(size_t)row * N + col] = acc[mt][nt][r];
        }
  }
}

// ---------------- 3-term split GEMM for Q||K projection -> frag-major panels ----
__global__ __launch_bounds__(256) void gemm_qk_kernel(
    const u16* __restrict__ Ah, const u16* __restrict__ Al,
    const u16* __restrict__ Bh, const u16* __restrict__ Bl,
    u16* __restrict__ Qhf, u16* __restrict__ Qlf,
    u16* __restrict__ Khf, u16* __restrict__ Klf, int M, int N, int K)
{
  __shared__ __attribute__((aligned(16))) u16 lAh[4096], lAl[4096], lBh[4096], lBl[4096];
  const int tid = threadIdx.x, lane = tid & 63, wave = tid >> 6;
  const int quad = lane >> 4, l15 = lane & 15;
  const int row0 = blockIdx.x * 128, col0 = blockIdx.y * 128;
  const int wm = wave >> 1, wn = wave & 1;
  const int sr = lane >> 2, sc = (lane & 3) * 8;
  f32x4 acc[4][4];
#pragma unroll
  for (int mt = 0; mt < 4; mt++)
#pragma unroll
    for (int nt = 0; nt < 4; nt++) acc[mt][nt] = (f32x4)0.0f;

  for (int k0 = 0; k0 < K; k0 += 32){
#pragma unroll
    for (int i = 0; i < 2; i++){
      int c = wave * 2 + i;
      size_t ao = (size_t)(row0 + c * 16 + sr) * K + k0 + sc;
      size_t bo = (size_t)(col0 + c * 16 + sr) * K + k0 + sc;
      gld16(Ah + ao, &lAh[c * 512]);
      gld16(Al + ao, &lAl[c * 512]);
      gld16(Bh + bo, &lBh[c * 512]);
      gld16(Bl + bo, &lBl[c * 512]);
    }
    __syncthreads();
    bf16x8 ah[4], al[4], bh[4], bl[4];
#pragma unroll
    for (int t = 0; t < 4; t++){
      int aoff = (wm * 64 + t * 16 + l15) * 32 + quad * 8;
      int boff = (wn * 64 + t * 16 + l15) * 32 + quad * 8;
      ah[t] = ldsfrag(&lAh[aoff]);  al[t] = ldsfrag(&lAl[aoff]);
      bh[t] = ldsfrag(&lBh[boff]);  bl[t] = ldsfrag(&lBl[boff]);
    }
#pragma unroll
    for (int mt = 0; mt < 4; mt++)
#pragma unroll
      for (int nt = 0; nt < 4; nt++){
        acc[mt][nt] = MFMA16(al[mt], bh[nt], acc[mt][nt]);
        acc[mt][nt] = MFMA16(ah[mt], bl[nt], acc[mt][nt]);
        acc[mt][nt] = MFMA16(ah[mt], bh[nt], acc[mt][nt]);
      }
    __syncthreads();
  }
  const bool isQ = (col0 < 1024);
#pragma unroll
  for (int mt = 0; mt < 4; mt++)
#pragma unroll
    for (int nt = 0; nt < 4; nt++)
#pragma unroll
      for (int r = 0; r < 4; r++){
        int row = row0 + wm * 64 + mt * 16 + quad * 4 + r;
        int col = col0 + wn * 64 + nt * 16 + l15;
        int bb = row >> 10, tt = row & 1023;
        int hh = (col >> 6) & 15, d = col & 63;
        int bhI = bb * 16 + hh;
        int kc = d >> 5, qF = (d >> 3) & 3, j = d & 7;
        float v = acc[mt][nt][r];
        u16 hi = f2b(v);
        u16 lo = f2b(v - b2f(hi));
        if (isQ){
          int qtile = tt >> 7, rr = tt & 127;
          int wv = rr >> 5, mtF = (rr >> 4) & 1, l15F = tt & 15;
          size_t idx = ((((size_t)(bhI * 8 + qtile) * 4 + wv) * 2 + mtF) * 2 + kc) * 512
                       + (qF * 16 + l15F) * 8 + j;
          Qhf[idx] = hi; Qlf[idx] = lo;
        } else {
          int ktile = tt >> 7, fkt = (tt >> 4) & 7, l15F = tt & 15;
          size_t idx = (((size_t)(bhI * 8 + ktile) * 8 + fkt) * 2 + kc) * 512
                       + (qF * 16 + l15F) * 8 + j;
          Khf[idx] = hi; Klf[idx] = lo;
        }
      }
}

// ---------------- flash attention (S^T, frag-major, 256-q-row blocks) --------
// grid = 512, block = 512 (8 waves, each owning 32 q-rows).
// Swizzle: qt = bid>>7 (0..3), bh = bid&127 => same-bh blocks are 128 apart
// => same XCD => K/V panels L2-shared across the 4 q-blocks of each (b,h).
__global__ __launch_bounds__(512, 4) void attn_kernel(
    const u16* __restrict__ Qhf, const u16* __restrict__ Qlf,
    const u16* __restrict__ Khf, const u16* __restrict__ Klf,
    const u16* __restrict__ Vf, u16* __restrict__ O)
{
  __shared__ __attribute__((aligned(16))) u16 lds[24576];   // 48KB
  u16* lKh = lds;            // [8][2][512] per kt
  u16* lKl = lds + 8192;
  u16* lV  = lds + 16384;    // [8][4][256] per kt
  const int tid = threadIdx.x, lane = tid & 63, wave = tid >> 6;  // wave 0..7
  const int quad = lane >> 4, l15 = lane & 15;
  const int qt = blockIdx.x >> 7, bh = blockIdx.x & 127;
  const int b = bh >> 4, h = bh & 15;
  const int q0 = qt * 256;
  const float BETA = 0.18033688011112042f;   // (1/sqrt(64)) * log2(e)

  bf16x8 qh[2][2], ql[2][2];
  { // two-phase Q staging (hi then lo) through the full 48KB as scratch
    int qtileL = qt * 2 + (wave >> 2), wv = wave & 3;
    size_t qbase = ((size_t)(bh * 8 + qtileL) * 4 + wv) * 2048 + lane * 8;
#pragma unroll
    for (int i = 0; i < 4; i++)
      gld16(Qhf + qbase + i * 512, &lds[wave * 2048 + i * 512]);
    __syncthreads();
#pragma unroll
    for (int mt = 0; mt < 2; mt++)
#pragma unroll
      for (int kc = 0; kc < 2; kc++)
        qh[mt][kc] = ldsfrag(&lds[wave * 2048 + (mt * 2 + kc) * 512 + lane * 8]);
    __syncthreads();
#pragma unroll
    for (int i = 0; i < 4; i++)
      gld16(Qlf + qbase + i * 512, &lds[wave * 2048 + i * 512]);
    __syncthreads();
#pragma unroll
    for (int mt = 0; mt < 2; mt++)
#pragma unroll
      for (int kc = 0; kc < 2; kc++)
        ql[mt][kc] = ldsfrag(&lds[wave * 2048 + (mt * 2 + kc) * 512 + lane * 8]);
    __syncthreads();
  }

  float m_i[2] = {-3.0e38f, -3.0e38f}, l_i[2] = {0.0f, 0.0f};
  f32x4 o_acc[2][4];
#pragma unroll
  for (int mt = 0; mt < 2; mt++)
#pragma unroll
    for (int nd = 0; nd < 4; nd++) o_acc[mt][nd] = (f32x4)0.0f;

  for (int kt = 0; kt < 8; kt++){
    size_t kpan = (size_t)(bh * 8 + kt) * 8192;
#pragma unroll
    for (int i = 0; i < 2; i++){
      int c = wave * 2 + i;                       // 0..15
      gld16(Khf + kpan + c * 512 + lane * 8, &lKh[c * 512]);
      gld16(Klf + kpan + c * 512 + lane * 8, &lKl[c * 512]);
      gld16(Vf  + kpan + c * 512 + lane * 8, &lV [c * 512]);
    }
    __syncthreads();

    // S^T = K.Q^T (A = K frags, B = Q frags), 3-term split
    f32x4 s[2][8];
#pragma unroll
    for (int qt2 = 0; qt2 < 2; qt2++)
#pragma unroll
      for (int fkt = 0; fkt < 8; fkt++) s[qt2][fkt] = (f32x4)0.0f;
#pragma unroll
    for (int fkt = 0; fkt < 8; fkt++){
      int aoff = fkt * 1024 + lane * 8;      // lane-linear, conflict-free
      bf16x8 kh0 = ldsfrag(&lKh[aoff]);
      bf16x8 kh1 = ldsfrag(&lKh[aoff + 512]);
      bf16x8 kl0 = ldsfrag(&lKl[aoff]);
      bf16x8 kl1 = ldsfrag(&lKl[aoff + 512]);
#pragma unroll
      for (int qt2 = 0; qt2 < 2; qt2++){
        s[qt2][fkt] = MFMA16(kl0, qh[qt2][0], s[qt2][fkt]);
        s[qt2][fkt] = MFMA16(kl1, qh[qt2][1], s[qt2][fkt]);
        s[qt2][fkt] = MFMA16(kh0, ql[qt2][0], s[qt2][fkt]);
        s[qt2][fkt] = MFMA16(kh1, ql[qt2][1], s[qt2][fkt]);
        s[qt2][fkt] = MFMA16(kh0, qh[qt2][0], s[qt2][fkt]);
        s[qt2][fkt] = MFMA16(kh1, qh[qt2][1], s[qt2][fkt]);
      }
    }

    // online softmax: lane l15 = q; 32 k-values in-lane, 2 shuffles finish
    float alpha[2];
#pragma unroll
    for (int qt2 = 0; qt2 < 2; qt2++){
      float mx = s[qt2][0][0];
#pragma unroll
      for (int fkt = 0; fkt < 8; fkt++)
#pragma unroll
        for (int r = 0; r < 4; r++) mx = fmaxf(mx, s[qt2][fkt][r]);
      mx = fmaxf(mx, __shfl_xor(mx, 16));
      mx = fmaxf(mx, __shfl_xor(mx, 32));
      float mn = fmaxf(m_i[qt2], mx);
      alpha[qt2] = __builtin_amdgcn_exp2f((m_i[qt2] - mn) * BETA);
      m_i[qt2] = mn;
      float mb = mn * BETA;
      float rs = 0.0f;
#pragma unroll
      for (int fkt = 0; fkt < 8; fkt++)
#pragma unroll
        for (int r = 0; r < 4; r++){
          float p = __builtin_amdgcn_exp2f(s[qt2][fkt][r] * BETA - mb);
          s[qt2][fkt][r] = p;
          rs += p;
        }
      rs += __shfl_xor(rs, 16);
      rs += __shfl_xor(rs, 32);
      l_i[qt2] = l_i[qt2] * alpha[qt2] + rs;
    }

    // rescale O (alpha at lane l15=q -> broadcast to O row layout)
#pragma unroll
    for (int mt = 0; mt < 2; mt++)
#pragma unroll
      for (int r = 0; r < 4; r++){
        float ar = __shfl(alpha[mt], quad * 4 + r);
#pragma unroll
        for (int nd = 0; nd < 4; nd++) o_acc[mt][nd][r] *= ar;
      }

    // PV via 16x16x16 MFMA; P already in A-frag layout; V frags lane-linear b64
#pragma unroll
    for (int fkt = 0; fkt < 8; fkt++){
      s16x4 vb[4];
#pragma unroll
      for (int nd = 0; nd < 4; nd++)
        vb[nd] = __builtin_bit_cast(s16x4,
                   *(const u16x4*)&lV[(fkt * 4 + nd) * 256 + lane * 4]);
#pragma unroll
      for (int qt2 = 0; qt2 < 2; qt2++){
        u32x2 pd;
        pd[0] = packhi(s[qt2][fkt][1], s[qt2][fkt][0]);
        pd[1] = packhi(s[qt2][fkt][3], s[qt2][fkt][2]);
        s16x4 pa = __builtin_bit_cast(s16x4, pd);
#pragma unroll
        for (int nd = 0; nd < 4; nd++)
          o_acc[qt2][nd] = MFMA16K16(pa, vb[nd], o_acc[qt2][nd]);
      }
    }
    __syncthreads();
  }

#pragma unroll
  for (int mt = 0; mt < 2; mt++)
#pragma unroll
    for (int r = 0; r < 4; r++){
      float lr = __shfl(l_i[mt], quad * 4 + r);
      float inv = 1.0f / lr;
      int t = q0 + wave * 32 + mt * 16 + quad * 4 + r;
      size_t rowoff = (size_t)(b * 1024 + t) * 1024 + h * 64;
#pragma unroll
      for (int nd = 0; nd < 4; nd++)
        O[rowoff + nd * 16 + l15] = f2b(o_acc[mt][nd][r] * inv);
    }
}

// ---------------- launcher ----------------
extern "C" void kernel_launch(void* const* d_in, const int* in_sizes, int n_in,
                              void* d_out, int out_size, void* d_ws, size_t ws_size,
                              hipStream_t stream)
{
  const float* x  = (const float*)d_in[0];
  const float* Wq = (const float*)d_in[1];
  const float* Wk = (const float*)d_in[2];
  const float* Wv = (const float*)d_in[3];
  const float* Wp = (const float*)d_in[4];
  float* out = (float*)d_out;
  char* ws = (char*)d_ws;
  const size_t MB = 1024 * 1024;
  // workspace map (peak 124 MB):
  u16* xh   = (u16*)(ws + 0);        // 16MB; reused as O after V-GEMM
  u16* xl   = (u16*)(ws + 16 * MB);  // 16MB
  u16* wqkh = (u16*)(ws + 32 * MB);  // 4MB  [2048][1024]
  u16* wqkl = (u16*)(ws + 36 * MB);  // 4MB
  u16* wvt  = (u16*)(ws + 40 * MB);  // 2MB
  u16* wpt  = (u16*)(ws + 42 * MB);  // 2MB
  u16* Qhf  = (u16*)(ws + 44 * MB);  // 16MB frag-major Q hi
  u16* Qlf  = (u16*)(ws + 60 * MB);  // 16MB frag-major Q lo
  u16* Khf  = (u16*)(ws + 76 * MB);  // 16MB frag-major K hi
  u16* Klf  = (u16*)(ws + 92 * MB);  // 16MB frag-major K lo
  u16* Vf   = (u16*)(ws + 108 * MB); // 16MB frag-major V
  u16* obuf = xh;
  (void)in_sizes; (void)n_in; (void)out_size; (void)ws_size;

  dim3 tb(32, 8);
  split_x_kernel<<<4096, 256, 0, stream>>>(x, xh, xl, 8 * 1024 * 1024);
  transpose_split_kernel<<<dim3(32, 32), tb, 0, stream>>>(Wq, wqkh, wqkl, 1024, 1024);
  transpose_split_kernel<<<dim3(32, 32), tb, 0, stream>>>(Wk, wqkh + 1024 * 1024, wqkl + 1024 * 1024, 1024, 1024);
  transpose_split_kernel<<<dim3(32, 32), tb, 0, stream>>>(Wv, wvt, (u16*)nullptr, 1024, 1024);
  transpose_split_kernel<<<dim3(32, 32), tb, 0, stream>>>(Wp, wpt, (u16*)nullptr, 1024, 1024);
  gemm_qk_kernel<<<dim3(64, 16), 256, 0, stream>>>(xh, xl, wqkh, wqkl,
                                                   Qhf, Qlf, Khf, Klf, 8192, 2048, 1024);
  gemm_bt_kernel<2><<<dim3(64, 8), 256, 0, stream>>>(xh, wvt, (void*)Vf, 8192, 1024, 1024);
  attn_kernel<<<512, 512, 0, stream>>>(Qhf, Qlf, Khf, Klf, Vf, obuf);
  gemm_bt_kernel<0><<<dim3(64, 8), 256, 0, stream>>>(obuf, wpt, (void*)out, 8192, 1024, 1024);
}

// Round 5
// 359.050 us; speedup vs baseline: 1.2348x; 1.2348x over previous
//
#include <hip/hip_runtime.h>
#include <math.h>

// MHA fwd: B=8 H=16 T=1024 D=1024 dh=64. fp32 in/out, bf16 MFMA compute.
// Split-bf16 (hi+lo) 3-term MFMA for x@Wq, x@Wk and Q@K^T (logits sigma~1024
// need ~fp32 accuracy; 2-term and int8 variants fail the error budget).
// R1: S^T = K.Q^T formulation (softmax in-lane, P = A-frag of 16x16x16 MFMA).
// R2: Q/K/V frag-major panels + XCD swizzle (conflict-free LDS, L2 reuse).
// R3: V frag layout fused into V-GEMM epilogue.
// R4 FAILED: 512-thr + launch_bounds(512,4) spilled P to scratch (343MB WRITE).
// R5: back to 256-thr/128-q-rows; S chunked into two 64-key halves so peak
//     live regs ~145 < 170 cap at (256,3) => no spill, 3 blocks/CU.

typedef unsigned short u16;
typedef unsigned int u32;
typedef __bf16  bf16x8 __attribute__((ext_vector_type(8)));
typedef unsigned short u16x8 __attribute__((ext_vector_type(8)));
typedef unsigned short u16x4 __attribute__((ext_vector_type(4)));
typedef short s16x4 __attribute__((ext_vector_type(4)));
typedef unsigned int u32x2 __attribute__((ext_vector_type(2)));
typedef float f32x4 __attribute__((ext_vector_type(4)));

#define MFMA16(a,b,c) __builtin_amdgcn_mfma_f32_16x16x32_bf16((a),(b),(c),0,0,0)
#define MFMA16K16(a,b,c) __builtin_amdgcn_mfma_f32_16x16x16bf16_1k((a),(b),(c),0,0,0)

static __device__ __forceinline__ u16 f2b(float f){
  unsigned u = __builtin_bit_cast(unsigned, f);
  u += 0x7fffu + ((u >> 16) & 1u);            // RNE
  return (u16)(u >> 16);
}
static __device__ __forceinline__ float b2f(u16 h){
  unsigned u = ((unsigned)h) << 16;
  return __builtin_bit_cast(float, u);
}
static __device__ __forceinline__ bf16x8 ldsfrag(const u16* p){
  return __builtin_bit_cast(bf16x8, *(const u16x8*)p);
}
static __device__ __forceinline__ u32 packhi(float fa, float fb){
  return __builtin_amdgcn_perm(__builtin_bit_cast(u32, fa),
                               __builtin_bit_cast(u32, fb), 0x07060302u);
}
static __device__ __forceinline__ void gld16(const void* g, void* l){
  __builtin_amdgcn_global_load_lds(
      (const __attribute__((address_space(1))) void*)g,
      (__attribute__((address_space(3))) void*)l, 16, 0, 0);
}

// Frag-major panel conventions (u16 index), bh = b*16+h, tt = t&1023, d in [0,64):
//  K (A-frag of 16x16x32):  ktile=tt>>7 fkt=(tt>>4)&7 l15=tt&15 | kc=d>>5 q=(d>>3)&3 j=d&7
//    idx = (((bh*8+ktile)*8+fkt)*2+kc)*512 + (q*16+l15)*8 + j          [16KB/ktile]
//  Q (B-frag of 16x16x32):  qtile=tt>>7 r=tt&127 wv=r>>5 mt=(r>>4)&1 l15=tt&15
//    idx = ((((bh*8+qtile)*4+wv)*2+mt)*2+kc)*512 + (q*16+l15)*8 + j    [16KB/qtile]
//  V (B-frag of 16x16x16):  ktile=tt>>7 fkt=(tt>>4)&7 q=(tt>>2)&3 j=tt&3 | nd=d>>4 l15=d&15
//    idx = ((((bh*8+ktile)*8+fkt)*4+nd)*64 + q*16+l15)*4 + j           [16KB/ktile]

// ---------------- split x (fp32 -> hi/lo bf16) ----------------
__global__ __launch_bounds__(256) void split_x_kernel(
    const float* __restrict__ x, u16* __restrict__ xh, u16* __restrict__ xl, int n)
{
  int i = (blockIdx.x * 256 + threadIdx.x) * 8;
  if (i >= n) return;
  float4 v0 = *(const float4*)(x + i);
  float4 v1 = *(const float4*)(x + i + 4);
  float vv[8] = {v0.x, v0.y, v0.z, v0.w, v1.x, v1.y, v1.z, v1.w};
  u16x8 hv, lv;
#pragma unroll
  for (int j = 0; j < 8; j++){
    u16 hb = f2b(vv[j]);
    hv[j] = hb;
    lv[j] = f2b(vv[j] - b2f(hb));
  }
  *(u16x8*)(xh + i) = hv;
  *(u16x8*)(xl + i) = lv;
}

// ---------------- transpose W (fp32 KxN -> bf16 NxK, optional lo) ----------------
__global__ __launch_bounds__(256) void transpose_split_kernel(
    const float* __restrict__ W, u16* __restrict__ Th, u16* __restrict__ Tl,
    int KD, int ND)
{
  __shared__ float t[32][33];
  int n0 = blockIdx.x * 32, k0 = blockIdx.y * 32;
  int tx = threadIdx.x, ty = threadIdx.y;
#pragma unroll
  for (int i = 0; i < 4; i++){
    int k = k0 + ty + i * 8;
    t[ty + i * 8][tx] = W[(size_t)k * ND + n0 + tx];
  }
  __syncthreads();
#pragma unroll
  for (int i = 0; i < 4; i++){
    int n = n0 + ty + i * 8;
    float v = t[tx][ty + i * 8];
    u16 h = f2b(v);
    Th[(size_t)n * KD + k0 + tx] = h;
    if (Tl) Tl[(size_t)n * KD + k0 + tx] = f2b(v - b2f(h));
  }
}

// ---------------- plain bf16 GEMM: C = A * Bt^T ----------------
// OUTMODE 0: fp32 row-major C[M][N].  OUTMODE 2: bf16 V-frag panels (N=1024).
template<int OUTMODE>
__global__ __launch_bounds__(256) void gemm_bt_kernel(
    const u16* __restrict__ A, const u16* __restrict__ Bt, void* __restrict__ Cv,
    int M, int N, int K)
{
  __shared__ __attribute__((aligned(16))) u16 lA[4096], lB[4096];
  const int tid = threadIdx.x, lane = tid & 63, wave = tid >> 6;
  const int quad = lane >> 4, l15 = lane & 15;
  const int row0 = blockIdx.x * 128, col0 = blockIdx.y * 128;
  const int wm = wave >> 1, wn = wave & 1;
  const int sr = lane >> 2, sc = (lane & 3) * 8;
  f32x4 acc[4][4];
#pragma unroll
  for (int mt = 0; mt < 4; mt++)
#pragma unroll
    for (int nt = 0; nt < 4; nt++) acc[mt][nt] = (f32x4)0.0f;

  for (int k0 = 0; k0 < K; k0 += 32){
#pragma unroll
    for (int i = 0; i < 2; i++){
      int c = wave * 2 + i;
      gld16(A  + (size_t)(row0 + c * 16 + sr) * K + k0 + sc, &lA[c * 512]);
      gld16(Bt + (size_t)(col0 + c * 16 + sr) * K + k0 + sc, &lB[c * 512]);
    }
    __syncthreads();
    bf16x8 a[4], b[4];
#pragma unroll
    for (int t = 0; t < 4; t++){
      a[t] = ldsfrag(&lA[(wm * 64 + t * 16 + l15) * 32 + quad * 8]);
      b[t] = ldsfrag(&lB[(wn * 64 + t * 16 + l15) * 32 + quad * 8]);
    }
#pragma unroll
    for (int mt = 0; mt < 4; mt++)
#pragma unroll
      for (int nt = 0; nt < 4; nt++)
        acc[mt][nt] = MFMA16(a[mt], b[nt], acc[mt][nt]);
    __syncthreads();
  }
  if (OUTMODE == 2){
    // V-frag epilogue: j = r (contiguous) -> one u16x4 store per (mt,nt)
#pragma unroll
    for (int mt = 0; mt < 4; mt++)
#pragma unroll
      for (int nt = 0; nt < 4; nt++){
        int row = row0 + wm * 64 + mt * 16 + quad * 4;
        int col = col0 + wn * 64 + nt * 16 + l15;
        int bb = row >> 10, tt = row & 1023;
        int hh = (col >> 6) & 15, d = col & 63;
        int bhI = bb * 16 + hh;
        int ktile = tt >> 7, fkt = (tt >> 4) & 7, qF = (tt >> 2) & 3;
        int nd = d >> 4, l15F = d & 15;
        size_t idx = ((((size_t)(bhI * 8 + ktile) * 8 + fkt) * 4 + nd) * 64
                      + qF * 16 + l15F) * 4;
        u16x4 vals;
#pragma unroll
        for (int r = 0; r < 4; r++) vals[r] = f2b(acc[mt][nt][r]);
        *(u16x4*)(((u16*)Cv) + idx) = vals;
      }
  } else {
#pragma unroll
    for (int mt = 0; mt < 4; mt++)
#pragma unroll
      for (int nt = 0; nt < 4; nt++)
#pragma unroll
        for (int r = 0; r < 4; r++){
          int row = row0 + wm * 64 + mt * 16 + quad * 4 + r;
          int col = col0 + wn * 64 + nt * 16 + l15;
          ((float*)Cv)[(size_t)row * N + col] = acc[mt][nt][r];
        }
  }
}

// ---------------- 3-term split GEMM for Q||K projection -> frag-major panels ----
__global__ __launch_bounds__(256) void gemm_qk_kernel(
    const u16* __restrict__ Ah, const u16* __restrict__ Al,
    const u16* __restrict__ Bh, const u16* __restrict__ Bl,
    u16* __restrict__ Qhf, u16* __restrict__ Qlf,
    u16* __restrict__ Khf, u16* __restrict__ Klf, int M, int N, int K)
{
  __shared__ __attribute__((aligned(16))) u16 lAh[4096], lAl[4096], lBh[4096], lBl[4096];
  const int tid = threadIdx.x, lane = tid & 63, wave = tid >> 6;
  const int quad = lane >> 4, l15 = lane & 15;
  const int row0 = blockIdx.x * 128, col0 = blockIdx.y * 128;
  const int wm = wave >> 1, wn = wave & 1;
  const int sr = lane >> 2, sc = (lane & 3) * 8;
  f32x4 acc[4][4];
#pragma unroll
  for (int mt = 0; mt < 4; mt++)
#pragma unroll
    for (int nt = 0; nt < 4; nt++) acc[mt][nt] = (f32x4)0.0f;

  for (int k0 = 0; k0 < K; k0 += 32){
#pragma unroll
    for (int i = 0; i < 2; i++){
      int c = wave * 2 + i;
      size_t ao = (size_t)(row0 + c * 16 + sr) * K + k0 + sc;
      size_t bo = (size_t)(col0 + c * 16 + sr) * K + k0 + sc;
      gld16(Ah + ao, &lAh[c * 512]);
      gld16(Al + ao, &lAl[c * 512]);
      gld16(Bh + bo, &lBh[c * 512]);
      gld16(Bl + bo, &lBl[c * 512]);
    }
    __syncthreads();
    bf16x8 ah[4], al[4], bh[4], bl[4];
#pragma unroll
    for (int t = 0; t < 4; t++){
      int aoff = (wm * 64 + t * 16 + l15) * 32 + quad * 8;
      int boff = (wn * 64 + t * 16 + l15) * 32 + quad * 8;
      ah[t] = ldsfrag(&lAh[aoff]);  al[t] = ldsfrag(&lAl[aoff]);
      bh[t] = ldsfrag(&lBh[boff]);  bl[t] = ldsfrag(&lBl[boff]);
    }
#pragma unroll
    for (int mt = 0; mt < 4; mt++)
#pragma unroll
      for (int nt = 0; nt < 4; nt++){
        acc[mt][nt] = MFMA16(al[mt], bh[nt], acc[mt][nt]);
        acc[mt][nt] = MFMA16(ah[mt], bl[nt], acc[mt][nt]);
        acc[mt][nt] = MFMA16(ah[mt], bh[nt], acc[mt][nt]);
      }
    __syncthreads();
  }
  const bool isQ = (col0 < 1024);
#pragma unroll
  for (int mt = 0; mt < 4; mt++)
#pragma unroll
    for (int nt = 0; nt < 4; nt++)
#pragma unroll
      for (int r = 0; r < 4; r++){
        int row = row0 + wm * 64 + mt * 16 + quad * 4 + r;
        int col = col0 + wn * 64 + nt * 16 + l15;
        int bb = row >> 10, tt = row & 1023;
        int hh = (col >> 6) & 15, d = col & 63;
        int bhI = bb * 16 + hh;
        int kc = d >> 5, qF = (d >> 3) & 3, j = d & 7;
        float v = acc[mt][nt][r];
        u16 hi = f2b(v);
        u16 lo = f2b(v - b2f(hi));
        if (isQ){
          int qtile = tt >> 7, rr = tt & 127;
          int wv = rr >> 5, mtF = (rr >> 4) & 1, l15F = tt & 15;
          size_t idx = ((((size_t)(bhI * 8 + qtile) * 4 + wv) * 2 + mtF) * 2 + kc) * 512
                       + (qF * 16 + l15F) * 8 + j;
          Qhf[idx] = hi; Qlf[idx] = lo;
        } else {
          int ktile = tt >> 7, fkt = (tt >> 4) & 7, l15F = tt & 15;
          size_t idx = (((size_t)(bhI * 8 + ktile) * 8 + fkt) * 2 + kc) * 512
                       + (qF * 16 + l15F) * 8 + j;
          Khf[idx] = hi; Klf[idx] = lo;
        }
      }
}

// ---------------- flash attention (S^T, frag-major, chunked softmax) --------
// grid = 1024, block = 256 (4 waves, each owning 32 q-rows of a 128-row tile).
// Swizzle: qt = bid>>7, bh = bid&127 => same-bh blocks 128 apart => same XCD.
// Each 128-key tile is processed as two 64-key halves so only s[2][4] (32
// VGPRs) of P is live at once => fits the (256,3) cap of ~170, no spill.
__global__ __launch_bounds__(256, 3) void attn_kernel(
    const u16* __restrict__ Qhf, const u16* __restrict__ Qlf,
    const u16* __restrict__ Khf, const u16* __restrict__ Klf,
    const u16* __restrict__ Vf, u16* __restrict__ O)
{
  __shared__ __attribute__((aligned(16))) u16 lKh[8192], lKl[8192], lV[8192];
  const int tid = threadIdx.x, lane = tid & 63, wave = tid >> 6;
  const int quad = lane >> 4, l15 = lane & 15;
  const int qt = blockIdx.x >> 7, bh = blockIdx.x & 127;
  const int b = bh >> 4, h = bh & 15;
  const int q0 = qt * 128;
  const float BETA = 0.18033688011112042f;   // (1/sqrt(64)) * log2(e)

  bf16x8 qh[2][2], ql[2][2];
  { // stage Q (frag-major, contiguous), keep B-frags in regs
    size_t qbase = (size_t)(bh * 8 + qt) * 8192 + wave * 2048 + lane * 8;
#pragma unroll
    for (int i = 0; i < 4; i++){
      gld16(Qhf + qbase + i * 512, &lKh[wave * 2048 + i * 512]);
      gld16(Qlf + qbase + i * 512, &lKl[wave * 2048 + i * 512]);
    }
    __syncthreads();
#pragma unroll
    for (int mt = 0; mt < 2; mt++)
#pragma unroll
      for (int kc = 0; kc < 2; kc++){
        int off = wave * 2048 + (mt * 2 + kc) * 512 + lane * 8;
        qh[mt][kc] = ldsfrag(&lKh[off]);
        ql[mt][kc] = ldsfrag(&lKl[off]);
      }
    __syncthreads();
  }

  float m_i[2] = {-3.0e38f, -3.0e38f}, l_i[2] = {0.0f, 0.0f};
  f32x4 o_acc[2][4];
#pragma unroll
  for (int mt = 0; mt < 2; mt++)
#pragma unroll
    for (int nd = 0; nd < 4; nd++) o_acc[mt][nd] = (f32x4)0.0f;

  for (int kt = 0; kt < 8; kt++){
    size_t kbase = (size_t)(bh * 8 + kt) * 8192 + wave * 2048 + lane * 8;
#pragma unroll
    for (int i = 0; i < 4; i++){
      gld16(Khf + kbase + i * 512, &lKh[wave * 2048 + i * 512]);
      gld16(Klf + kbase + i * 512, &lKl[wave * 2048 + i * 512]);
      gld16(Vf  + kbase + i * 512, &lV [wave * 2048 + i * 512]);
    }
    __syncthreads();

#pragma unroll 1
    for (int half = 0; half < 2; half++){
      // S^T = K.Q^T for 64 keys (A = K frags, B = Q frags), 3-term split
      f32x4 s[2][4];
#pragma unroll
      for (int qt2 = 0; qt2 < 2; qt2++)
#pragma unroll
        for (int f4 = 0; f4 < 4; f4++) s[qt2][f4] = (f32x4)0.0f;
#pragma unroll
      for (int f4 = 0; f4 < 4; f4++){
        int aoff = (half * 4 + f4) * 1024 + lane * 8;   // lane-linear
        bf16x8 kh0 = ldsfrag(&lKh[aoff]);
        bf16x8 kh1 = ldsfrag(&lKh[aoff + 512]);
        bf16x8 kl0 = ldsfrag(&lKl[aoff]);
        bf16x8 kl1 = ldsfrag(&lKl[aoff + 512]);
#pragma unroll
        for (int qt2 = 0; qt2 < 2; qt2++){
          s[qt2][f4] = MFMA16(kl0, qh[qt2][0], s[qt2][f4]);
          s[qt2][f4] = MFMA16(kl1, qh[qt2][1], s[qt2][f4]);
          s[qt2][f4] = MFMA16(kh0, ql[qt2][0], s[qt2][f4]);
          s[qt2][f4] = MFMA16(kh1, ql[qt2][1], s[qt2][f4]);
          s[qt2][f4] = MFMA16(kh0, qh[qt2][0], s[qt2][f4]);
          s[qt2][f4] = MFMA16(kh1, qh[qt2][1], s[qt2][f4]);
        }
      }

      // online softmax merge for this 64-key half (lane l15 = q; 16 in-lane)
      float alpha[2];
#pragma unroll
      for (int qt2 = 0; qt2 < 2; qt2++){
        float mx = s[qt2][0][0];
#pragma unroll
        for (int f4 = 0; f4 < 4; f4++)
#pragma unroll
          for (int r = 0; r < 4; r++) mx = fmaxf(mx, s[qt2][f4][r]);
        mx = fmaxf(mx, __shfl_xor(mx, 16));
        mx = fmaxf(mx, __shfl_xor(mx, 32));
        float mn = fmaxf(m_i[qt2], mx);
        alpha[qt2] = __builtin_amdgcn_exp2f((m_i[qt2] - mn) * BETA);
        m_i[qt2] = mn;
        float mb = mn * BETA;
        float rs = 0.0f;
#pragma unroll
        for (int f4 = 0; f4 < 4; f4++)
#pragma unroll
          for (int r = 0; r < 4; r++){
            float p = __builtin_amdgcn_exp2f(s[qt2][f4][r] * BETA - mb);
            s[qt2][f4][r] = p;
            rs += p;
          }
        rs += __shfl_xor(rs, 16);
        rs += __shfl_xor(rs, 32);
        l_i[qt2] = l_i[qt2] * alpha[qt2] + rs;
      }

      // rescale O (alpha at lane l15=q -> broadcast to O row layout)
#pragma unroll
      for (int mt = 0; mt < 2; mt++)
#pragma unroll
        for (int r = 0; r < 4; r++){
          float ar = __shfl(alpha[mt], quad * 4 + r);
#pragma unroll
          for (int nd = 0; nd < 4; nd++) o_acc[mt][nd][r] *= ar;
        }

      // PV via 16x16x16 MFMA; P already in A-frag layout; V lane-linear b64
#pragma unroll
      for (int f4 = 0; f4 < 4; f4++){
        int fkt = half * 4 + f4;
        s16x4 vb[4];
#pragma unroll
        for (int nd = 0; nd < 4; nd++)
          vb[nd] = __builtin_bit_cast(s16x4,
                     *(const u16x4*)&lV[(fkt * 4 + nd) * 256 + lane * 4]);
#pragma unroll
        for (int qt2 = 0; qt2 < 2; qt2++){
          u32x2 pd;
          pd[0] = packhi(s[qt2][f4][1], s[qt2][f4][0]);
          pd[1] = packhi(s[qt2][f4][3], s[qt2][f4][2]);
          s16x4 pa = __builtin_bit_cast(s16x4, pd);
#pragma unroll
          for (int nd = 0; nd < 4; nd++)
            o_acc[qt2][nd] = MFMA16K16(pa, vb[nd], o_acc[qt2][nd]);
        }
      }
    }
    __syncthreads();
  }

#pragma unroll
  for (int mt = 0; mt < 2; mt++)
#pragma unroll
    for (int r = 0; r < 4; r++){
      float lr = __shfl(l_i[mt], quad * 4 + r);
      float inv = 1.0f / lr;
      int t = q0 + wave * 32 + mt * 16 + quad * 4 + r;
      size_t rowoff = (size_t)(b * 1024 + t) * 1024 + h * 64;
#pragma unroll
      for (int nd = 0; nd < 4; nd++)
        O[rowoff + nd * 16 + l15] = f2b(o_acc[mt][nd][r] * inv);
    }
}

// ---------------- launcher ----------------
extern "C" void kernel_launch(void* const* d_in, const int* in_sizes, int n_in,
                              void* d_out, int out_size, void* d_ws, size_t ws_size,
                              hipStream_t stream)
{
  const float* x  = (const float*)d_in[0];
  const float* Wq = (const float*)d_in[1];
  const float* Wk = (const float*)d_in[2];
  const float* Wv = (const float*)d_in[3];
  const float* Wp = (const float*)d_in[4];
  float* out = (float*)d_out;
  char* ws = (char*)d_ws;
  const size_t MB = 1024 * 1024;
  // workspace map (peak 124 MB):
  u16* xh   = (u16*)(ws + 0);        // 16MB; reused as O after V-GEMM
  u16* xl   = (u16*)(ws + 16 * MB);  // 16MB
  u16* wqkh = (u16*)(ws + 32 * MB);  // 4MB  [2048][1024]
  u16* wqkl = (u16*)(ws + 36 * MB);  // 4MB
  u16* wvt  = (u16*)(ws + 40 * MB);  // 2MB
  u16* wpt  = (u16*)(ws + 42 * MB);  // 2MB
  u16* Qhf  = (u16*)(ws + 44 * MB);  // 16MB frag-major Q hi
  u16* Qlf  = (u16*)(ws + 60 * MB);  // 16MB frag-major Q lo
  u16* Khf  = (u16*)(ws + 76 * MB);  // 16MB frag-major K hi
  u16* Klf  = (u16*)(ws + 92 * MB);  // 16MB frag-major K lo
  u16* Vf   = (u16*)(ws + 108 * MB); // 16MB frag-major V
  u16* obuf = xh;
  (void)in_sizes; (void)n_in; (void)out_size; (void)ws_size;

  dim3 tb(32, 8);
  split_x_kernel<<<4096, 256, 0, stream>>>(x, xh, xl, 8 * 1024 * 1024);
  transpose_split_kernel<<<dim3(32, 32), tb, 0, stream>>>(Wq, wqkh, wqkl, 1024, 1024);
  transpose_split_kernel<<<dim3(32, 32), tb, 0, stream>>>(Wk, wqkh + 1024 * 1024, wqkl + 1024 * 1024, 1024, 1024);
  transpose_split_kernel<<<dim3(32, 32), tb, 0, stream>>>(Wv, wvt, (u16*)nullptr, 1024, 1024);
  transpose_split_kernel<<<dim3(32, 32), tb, 0, stream>>>(Wp, wpt, (u16*)nullptr, 1024, 1024);
  gemm_qk_kernel<<<dim3(64, 16), 256, 0, stream>>>(xh, xl, wqkh, wqkl,
                                                   Qhf, Qlf, Khf, Klf, 8192, 2048, 1024);
  gemm_bt_kernel<2><<<dim3(64, 8), 256, 0, stream>>>(xh, wvt, (void*)Vf, 8192, 1024, 1024);
  attn_kernel<<<1024, 256, 0, stream>>>(Qhf, Qlf, Khf, Klf, Vf, obuf);
  gemm_bt_kernel<0><<<dim3(64, 8), 256, 0, stream>>>(obuf, wpt, (void*)out, 8192, 1024, 1024);
}

// Round 6
// 355.210 us; speedup vs baseline: 1.2481x; 1.0108x over previous
//
#include <hip/hip_runtime.h>
#include <math.h>

// MHA fwd: B=8 H=16 T=1024 D=1024 dh=64. fp32 in/out, bf16 MFMA compute.
// Split-bf16 (hi+lo) 3-term MFMA for x@Wq, x@Wk and Q@K^T (logits sigma~1024
// need ~fp32 accuracy; 2-term and int8 variants fail the error budget).
// R1: S^T = K.Q^T formulation (softmax in-lane, P = A-frag of 16x16x16 MFMA).
// R2: Q/K/V frag-major panels + XCD swizzle (conflict-free LDS, L2 reuse).
// R3: V frag layout fused into V-GEMM epilogue.
// R4 FAILED: 512-thr launch_bounds(512,4) spilled P to scratch (343MB WRITE).
// R5: 64-key S chunking => no spill at (256,3).
// R6: attn K/V staging double-buffered at 64-key granularity (24KB/tile x2 =
//     48KB LDS, 3 blocks/CU kept). Barrier-then-prefetch order => each
//     barrier's vmcnt(0) drain finds loads a full compute phase old (attn
//     compute/tile ~1000+cyc > L2-hit latency, unlike the m97 GEMM case).
//     Plus: softmax denom tree-sum; 4 transpose launches fused into 1.

typedef unsigned short u16;
typedef unsigned int u32;
typedef __bf16  bf16x8 __attribute__((ext_vector_type(8)));
typedef unsigned short u16x8 __attribute__((ext_vector_type(8)));
typedef unsigned short u16x4 __attribute__((ext_vector_type(4)));
typedef short s16x4 __attribute__((ext_vector_type(4)));
typedef unsigned int u32x2 __attribute__((ext_vector_type(2)));
typedef float f32x4 __attribute__((ext_vector_type(4)));

#define MFMA16(a,b,c) __builtin_amdgcn_mfma_f32_16x16x32_bf16((a),(b),(c),0,0,0)
#define MFMA16K16(a,b,c) __builtin_amdgcn_mfma_f32_16x16x16bf16_1k((a),(b),(c),0,0,0)

static __device__ __forceinline__ u16 f2b(float f){
  unsigned u = __builtin_bit_cast(unsigned, f);
  u += 0x7fffu + ((u >> 16) & 1u);            // RNE
  return (u16)(u >> 16);
}
static __device__ __forceinline__ float b2f(u16 h){
  unsigned u = ((unsigned)h) << 16;
  return __builtin_bit_cast(float, u);
}
static __device__ __forceinline__ bf16x8 ldsfrag(const u16* p){
  return __builtin_bit_cast(bf16x8, *(const u16x8*)p);
}
static __device__ __forceinline__ u32 packhi(float fa, float fb){
  return __builtin_amdgcn_perm(__builtin_bit_cast(u32, fa),
                               __builtin_bit_cast(u32, fb), 0x07060302u);
}
static __device__ __forceinline__ void gld16(const void* g, void* l){
  __builtin_amdgcn_global_load_lds(
      (const __attribute__((address_space(1))) void*)g,
      (__attribute__((address_space(3))) void*)l, 16, 0, 0);
}

// Frag-major panel conventions (u16 index), bh = b*16+h, tt = t&1023, d in [0,64):
//  K (A-frag of 16x16x32):  ktile=tt>>7 fkt=(tt>>4)&7 l15=tt&15 | kc=d>>5 q=(d>>3)&3 j=d&7
//    idx = (((bh*8+ktile)*8+fkt)*2+kc)*512 + (q*16+l15)*8 + j          [16KB/ktile]
//  Q (B-frag of 16x16x32):  qtile=tt>>7 r=tt&127 wv=r>>5 mt=(r>>4)&1 l15=tt&15
//    idx = ((((bh*8+qtile)*4+wv)*2+mt)*2+kc)*512 + (q*16+l15)*8 + j    [16KB/qtile]
//  V (B-frag of 16x16x16):  ktile=tt>>7 fkt=(tt>>4)&7 q=(tt>>2)&3 j=tt&3 | nd=d>>4 l15=d&15
//    idx = ((((bh*8+ktile)*8+fkt)*4+nd)*64 + q*16+l15)*4 + j           [16KB/ktile]
// 64-key granularity: tile j (0..15) of a bh = contiguous 4096-u16 block at
//   panel_base(bh) + j*4096 in each of K/Kl/V panels.

// ---------------- split x (fp32 -> hi/lo bf16) ----------------
__global__ __launch_bounds__(256) void split_x_kernel(
    const float* __restrict__ x, u16* __restrict__ xh, u16* __restrict__ xl, int n)
{
  int i = (blockIdx.x * 256 + threadIdx.x) * 8;
  if (i >= n) return;
  float4 v0 = *(const float4*)(x + i);
  float4 v1 = *(const float4*)(x + i + 4);
  float vv[8] = {v0.x, v0.y, v0.z, v0.w, v1.x, v1.y, v1.z, v1.w};
  u16x8 hv, lv;
#pragma unroll
  for (int j = 0; j < 8; j++){
    u16 hb = f2b(vv[j]);
    hv[j] = hb;
    lv[j] = f2b(vv[j] - b2f(hb));
  }
  *(u16x8*)(xh + i) = hv;
  *(u16x8*)(xl + i) = lv;
}

// ---------------- fused transpose of all 4 weights (z selects matrix) --------
__global__ __launch_bounds__(256) void transpose4_kernel(
    const float* __restrict__ Wq, const float* __restrict__ Wk,
    const float* __restrict__ Wv, const float* __restrict__ Wp,
    u16* __restrict__ qh_, u16* __restrict__ ql_,
    u16* __restrict__ kh_, u16* __restrict__ kl_,
    u16* __restrict__ vt_, u16* __restrict__ pt_)
{
  __shared__ float t[32][33];
  const int z = blockIdx.z;
  const float* W = (z == 0) ? Wq : (z == 1) ? Wk : (z == 2) ? Wv : Wp;
  u16* Th = (z == 0) ? qh_ : (z == 1) ? kh_ : (z == 2) ? vt_ : pt_;
  u16* Tl = (z == 0) ? ql_ : (z == 1) ? kl_ : nullptr;
  int n0 = blockIdx.x * 32, k0 = blockIdx.y * 32;
  int tx = threadIdx.x, ty = threadIdx.y;
#pragma unroll
  for (int i = 0; i < 4; i++){
    int k = k0 + ty + i * 8;
    t[ty + i * 8][tx] = W[(size_t)k * 1024 + n0 + tx];
  }
  __syncthreads();
#pragma unroll
  for (int i = 0; i < 4; i++){
    int n = n0 + ty + i * 8;
    float v = t[tx][ty + i * 8];
    u16 h = f2b(v);
    Th[(size_t)n * 1024 + k0 + tx] = h;
    if (Tl) Tl[(size_t)n * 1024 + k0 + tx] = f2b(v - b2f(h));
  }
}

// ---------------- plain bf16 GEMM: C = A * Bt^T ----------------
// OUTMODE 0: fp32 row-major C[M][N].  OUTMODE 2: bf16 V-frag panels (N=1024).
template<int OUTMODE>
__global__ __launch_bounds__(256) void gemm_bt_kernel(
    const u16* __restrict__ A, const u16* __restrict__ Bt, void* __restrict__ Cv,
    int M, int N, int K)
{
  __shared__ __attribute__((aligned(16))) u16 lA[4096], lB[4096];
  const int tid = threadIdx.x, lane = tid & 63, wave = tid >> 6;
  const int quad = lane >> 4, l15 = lane & 15;
  const int row0 = blockIdx.x * 128, col0 = blockIdx.y * 128;
  const int wm = wave >> 1, wn = wave & 1;
  const int sr = lane >> 2, sc = (lane & 3) * 8;
  f32x4 acc[4][4];
#pragma unroll
  for (int mt = 0; mt < 4; mt++)
#pragma unroll
    for (int nt = 0; nt < 4; nt++) acc[mt][nt] = (f32x4)0.0f;

  for (int k0 = 0; k0 < K; k0 += 32){
#pragma unroll
    for (int i = 0; i < 2; i++){
      int c = wave * 2 + i;
      gld16(A  + (size_t)(row0 + c * 16 + sr) * K + k0 + sc, &lA[c * 512]);
      gld16(Bt + (size_t)(col0 + c * 16 + sr) * K + k0 + sc, &lB[c * 512]);
    }
    __syncthreads();
    bf16x8 a[4], b[4];
#pragma unroll
    for (int t = 0; t < 4; t++){
      a[t] = ldsfrag(&lA[(wm * 64 + t * 16 + l15) * 32 + quad * 8]);
      b[t] = ldsfrag(&lB[(wn * 64 + t * 16 + l15) * 32 + quad * 8]);
    }
#pragma unroll
    for (int mt = 0; mt < 4; mt++)
#pragma unroll
      for (int nt = 0; nt < 4; nt++)
        acc[mt][nt] = MFMA16(a[mt], b[nt], acc[mt][nt]);
    __syncthreads();
  }
  if (OUTMODE == 2){
    // V-frag epilogue: j = r (contiguous) -> one u16x4 store per (mt,nt)
#pragma unroll
    for (int mt = 0; mt < 4; mt++)
#pragma unroll
      for (int nt = 0; nt < 4; nt++){
        int row = row0 + wm * 64 + mt * 16 + quad * 4;
        int col = col0 + wn * 64 + nt * 16 + l15;
        int bb = row >> 10, tt = row & 1023;
        int hh = (col >> 6) & 15, d = col & 63;
        int bhI = bb * 16 + hh;
        int ktile = tt >> 7, fkt = (tt >> 4) & 7, qF = (tt >> 2) & 3;
        int nd = d >> 4, l15F = d & 15;
        size_t idx = ((((size_t)(bhI * 8 + ktile) * 8 + fkt) * 4 + nd) * 64
                      + qF * 16 + l15F) * 4;
        u16x4 vals;
#pragma unroll
        for (int r = 0; r < 4; r++) vals[r] = f2b(acc[mt][nt][r]);
        *(u16x4*)(((u16*)Cv) + idx) = vals;
      }
  } else {
#pragma unroll
    for (int mt = 0; mt < 4; mt++)
#pragma unroll
      for (int nt = 0; nt < 4; nt++)
#pragma unroll
        for (int r = 0; r < 4; r++){
          int row = row0 + wm * 64 + mt * 16 + quad * 4 + r;
          int col = col0 + wn * 64 + nt * 16 + l15;
          ((float*)Cv)[(size_t)row * N + col] = acc[mt][nt][r];
        }
  }
}

// ---------------- 3-term split GEMM for Q||K projection -> frag-major panels ----
__global__ __launch_bounds__(256) void gemm_qk_kernel(
    const u16* __restrict__ Ah, const u16* __restrict__ Al,
    const u16* __restrict__ Bh, const u16* __restrict__ Bl,
    u16* __restrict__ Qhf, u16* __restrict__ Qlf,
    u16* __restrict__ Khf, u16* __restrict__ Klf, int M, int N, int K)
{
  __shared__ __attribute__((aligned(16))) u16 lAh[4096], lAl[4096], lBh[4096], lBl[4096];
  const int tid = threadIdx.x, lane = tid & 63, wave = tid >> 6;
  const int quad = lane >> 4, l15 = lane & 15;
  const int row0 = blockIdx.x * 128, col0 = blockIdx.y * 128;
  const int wm = wave >> 1, wn = wave & 1;
  const int sr = lane >> 2, sc = (lane & 3) * 8;
  f32x4 acc[4][4];
#pragma unroll
  for (int mt = 0; mt < 4; mt++)
#pragma unroll
    for (int nt = 0; nt < 4; nt++) acc[mt][nt] = (f32x4)0.0f;

  for (int k0 = 0; k0 < K; k0 += 32){
#pragma unroll
    for (int i = 0; i < 2; i++){
      int c = wave * 2 + i;
      size_t ao = (size_t)(row0 + c * 16 + sr) * K + k0 + sc;
      size_t bo = (size_t)(col0 + c * 16 + sr) * K + k0 + sc;
      gld16(Ah + ao, &lAh[c * 512]);
      gld16(Al + ao, &lAl[c * 512]);
      gld16(Bh + bo, &lBh[c * 512]);
      gld16(Bl + bo, &lBl[c * 512]);
    }
    __syncthreads();
    bf16x8 ah[4], al[4], bh[4], bl[4];
#pragma unroll
    for (int t = 0; t < 4; t++){
      int aoff = (wm * 64 + t * 16 + l15) * 32 + quad * 8;
      int boff = (wn * 64 + t * 16 + l15) * 32 + quad * 8;
      ah[t] = ldsfrag(&lAh[aoff]);  al[t] = ldsfrag(&lAl[aoff]);
      bh[t] = ldsfrag(&lBh[boff]);  bl[t] = ldsfrag(&lBl[boff]);
    }
#pragma unroll
    for (int mt = 0; mt < 4; mt++)
#pragma unroll
      for (int nt = 0; nt < 4; nt++){
        acc[mt][nt] = MFMA16(al[mt], bh[nt], acc[mt][nt]);
        acc[mt][nt] = MFMA16(ah[mt], bl[nt], acc[mt][nt]);
        acc[mt][nt] = MFMA16(ah[mt], bh[nt], acc[mt][nt]);
      }
    __syncthreads();
  }
  const bool isQ = (col0 < 1024);
#pragma unroll
  for (int mt = 0; mt < 4; mt++)
#pragma unroll
    for (int nt = 0; nt < 4; nt++)
#pragma unroll
      for (int r = 0; r < 4; r++){
        int row = row0 + wm * 64 + mt * 16 + quad * 4 + r;
        int col = col0 + wn * 64 + nt * 16 + l15;
        int bb = row >> 10, tt = row & 1023;
        int hh = (col >> 6) & 15, d = col & 63;
        int bhI = bb * 16 + hh;
        int kc = d >> 5, qF = (d >> 3) & 3, j = d & 7;
        float v = acc[mt][nt][r];
        u16 hi = f2b(v);
        u16 lo = f2b(v - b2f(hi));
        if (isQ){
          int qtile = tt >> 7, rr = tt & 127;
          int wv = rr >> 5, mtF = (rr >> 4) & 1, l15F = tt & 15;
          size_t idx = ((((size_t)(bhI * 8 + qtile) * 4 + wv) * 2 + mtF) * 2 + kc) * 512
                       + (qF * 16 + l15F) * 8 + j;
          Qhf[idx] = hi; Qlf[idx] = lo;
        } else {
          int ktile = tt >> 7, fkt = (tt >> 4) & 7, l15F = tt & 15;
          size_t idx = (((size_t)(bhI * 8 + ktile) * 8 + fkt) * 2 + kc) * 512
                       + (qF * 16 + l15F) * 8 + j;
          Khf[idx] = hi; Klf[idx] = lo;
        }
      }
}

// ---------------- flash attention (S^T, frag-major, 64-key dbuf tiles) -------
// grid = 1024, block = 256 (4 waves x 32 q-rows). qt = bid>>7, bh = bid&127
// (same-bh blocks 128 apart => same XCD => K/V L2-shared).
// 16 tiles of 64 keys; LDS double-buffered (2 x 24KB); barrier THEN prefetch
// order so each barrier's vmcnt(0) drain finds tile j's loads one full
// compute phase old.
__global__ __launch_bounds__(256, 3) void attn_kernel(
    const u16* __restrict__ Qhf, const u16* __restrict__ Qlf,
    const u16* __restrict__ Khf, const u16* __restrict__ Klf,
    const u16* __restrict__ Vf, u16* __restrict__ O)
{
  __shared__ __attribute__((aligned(16))) u16 lKh[2][4096], lKl[2][4096], lV[2][4096];
  const int tid = threadIdx.x, lane = tid & 63, wave = tid >> 6;
  const int quad = lane >> 4, l15 = lane & 15;
  const int qt = blockIdx.x >> 7, bh = blockIdx.x & 127;
  const int b = bh >> 4, h = bh & 15;
  const int q0 = qt * 128;
  const float BETA = 0.18033688011112042f;   // (1/sqrt(64)) * log2(e)

  bf16x8 qh[2][2], ql[2][2];
  { // stage Q through the (not-yet-used) double buffers as 16KB scratch
    size_t qbase = (size_t)(bh * 8 + qt) * 8192 + wave * 2048 + lane * 8;
    u16* sh = &lKh[0][0];  u16* sl = &lKl[0][0];   // flattened 2x4096
#pragma unroll
    for (int i = 0; i < 4; i++){
      gld16(Qhf + qbase + i * 512, sh + wave * 2048 + i * 512);
      gld16(Qlf + qbase + i * 512, sl + wave * 2048 + i * 512);
    }
    __syncthreads();
#pragma unroll
    for (int mt = 0; mt < 2; mt++)
#pragma unroll
      for (int kc = 0; kc < 2; kc++){
        int off = wave * 2048 + (mt * 2 + kc) * 512 + lane * 8;
        qh[mt][kc] = ldsfrag(sh + off);
        ql[mt][kc] = ldsfrag(sl + off);
      }
    __syncthreads();
  }

  float m_i[2] = {-3.0e38f, -3.0e38f}, l_i[2] = {0.0f, 0.0f};
  f32x4 o_acc[2][4];
#pragma unroll
  for (int mt = 0; mt < 2; mt++)
#pragma unroll
    for (int nd = 0; nd < 4; nd++) o_acc[mt][nd] = (f32x4)0.0f;

  const size_t pan = (size_t)bh * 65536;   // per-bh K/Kl/V panel base (u16)
  // prefetch tile 0 into buf 0 (2 chunks per array per wave)
#pragma unroll
  for (int i = 0; i < 2; i++){
    int c = wave * 2 + i;                  // 0..7 chunks of 512 u16
    gld16(Khf + pan + c * 512 + lane * 8, &lKh[0][c * 512]);
    gld16(Klf + pan + c * 512 + lane * 8, &lKl[0][c * 512]);
    gld16(Vf  + pan + c * 512 + lane * 8, &lV [0][c * 512]);
  }

#pragma unroll 1
  for (int j = 0; j < 16; j++){
    const int cur = j & 1;
    __syncthreads();                       // drains tile-j loads (1 phase old)
    if (j < 15){
      size_t nb = pan + (size_t)(j + 1) * 4096;
      const int nxt = cur ^ 1;
#pragma unroll
      for (int i = 0; i < 2; i++){
        int c = wave * 2 + i;
        gld16(Khf + nb + c * 512 + lane * 8, &lKh[nxt][c * 512]);
        gld16(Klf + nb + c * 512 + lane * 8, &lKl[nxt][c * 512]);
        gld16(Vf  + nb + c * 512 + lane * 8, &lV [nxt][c * 512]);
      }
    }

    // S^T = K.Q^T for 64 keys (A = K frags, B = Q frags), 3-term split
    f32x4 s[2][4];
#pragma unroll
    for (int qt2 = 0; qt2 < 2; qt2++)
#pragma unroll
      for (int f4 = 0; f4 < 4; f4++) s[qt2][f4] = (f32x4)0.0f;
#pragma unroll
    for (int f4 = 0; f4 < 4; f4++){
      int aoff = f4 * 1024 + lane * 8;     // lane-linear, conflict-free
      bf16x8 kh0 = ldsfrag(&lKh[cur][aoff]);
      bf16x8 kh1 = ldsfrag(&lKh[cur][aoff + 512]);
      bf16x8 kl0 = ldsfrag(&lKl[cur][aoff]);
      bf16x8 kl1 = ldsfrag(&lKl[cur][aoff + 512]);
#pragma unroll
      for (int qt2 = 0; qt2 < 2; qt2++){
        s[qt2][f4] = MFMA16(kl0, qh[qt2][0], s[qt2][f4]);
        s[qt2][f4] = MFMA16(kl1, qh[qt2][1], s[qt2][f4]);
        s[qt2][f4] = MFMA16(kh0, ql[qt2][0], s[qt2][f4]);
        s[qt2][f4] = MFMA16(kh1, ql[qt2][1], s[qt2][f4]);
        s[qt2][f4] = MFMA16(kh0, qh[qt2][0], s[qt2][f4]);
        s[qt2][f4] = MFMA16(kh1, qh[qt2][1], s[qt2][f4]);
      }
    }

    // online softmax merge (lane l15 = q; 16 logits in-lane)
    float alpha[2];
#pragma unroll
    for (int qt2 = 0; qt2 < 2; qt2++){
      f32x4 mv = s[qt2][0];
#pragma unroll
      for (int f4 = 1; f4 < 4; f4++){
        mv[0] = fmaxf(mv[0], s[qt2][f4][0]); mv[1] = fmaxf(mv[1], s[qt2][f4][1]);
        mv[2] = fmaxf(mv[2], s[qt2][f4][2]); mv[3] = fmaxf(mv[3], s[qt2][f4][3]);
      }
      float mx = fmaxf(fmaxf(mv[0], mv[1]), fmaxf(mv[2], mv[3]));
      mx = fmaxf(mx, __shfl_xor(mx, 16));
      mx = fmaxf(mx, __shfl_xor(mx, 32));
      float mn = fmaxf(m_i[qt2], mx);
      alpha[qt2] = __builtin_amdgcn_exp2f((m_i[qt2] - mn) * BETA);
      m_i[qt2] = mn;
      float mb = mn * BETA;
      f32x4 ps = (f32x4)0.0f;
#pragma unroll
      for (int f4 = 0; f4 < 4; f4++)
#pragma unroll
        for (int r = 0; r < 4; r++){
          float p = __builtin_amdgcn_exp2f(s[qt2][f4][r] * BETA - mb);
          s[qt2][f4][r] = p;
          ps[r] += p;                      // 4 independent partial chains
        }
      float rs = (ps[0] + ps[1]) + (ps[2] + ps[3]);
      rs += __shfl_xor(rs, 16);
      rs += __shfl_xor(rs, 32);
      l_i[qt2] = l_i[qt2] * alpha[qt2] + rs;
    }

    // rescale O (alpha at lane l15=q -> broadcast to O row layout)
#pragma unroll
    for (int mt = 0; mt < 2; mt++)
#pragma unroll
      for (int r = 0; r < 4; r++){
        float ar = __shfl(alpha[mt], quad * 4 + r);
#pragma unroll
        for (int nd = 0; nd < 4; nd++) o_acc[mt][nd][r] *= ar;
      }

    // PV via 16x16x16 MFMA; P already in A-frag layout; V lane-linear b64
#pragma unroll
    for (int f4 = 0; f4 < 4; f4++){
      s16x4 vb[4];
#pragma unroll
      for (int nd = 0; nd < 4; nd++)
        vb[nd] = __builtin_bit_cast(s16x4,
                   *(const u16x4*)&lV[cur][(f4 * 4 + nd) * 256 + lane * 4]);
#pragma unroll
      for (int qt2 = 0; qt2 < 2; qt2++){
        u32x2 pd;
        pd[0] = packhi(s[qt2][f4][1], s[qt2][f4][0]);
        pd[1] = packhi(s[qt2][f4][3], s[qt2][f4][2]);
        s16x4 pa = __builtin_bit_cast(s16x4, pd);
#pragma unroll
        for (int nd = 0; nd < 4; nd++)
          o_acc[qt2][nd] = MFMA16K16(pa, vb[nd], o_acc[qt2][nd]);
      }
    }
  }

#pragma unroll
  for (int mt = 0; mt < 2; mt++)
#pragma unroll
    for (int r = 0; r < 4; r++){
      float lr = __shfl(l_i[mt], quad * 4 + r);
      float inv = 1.0f / lr;
      int t = q0 + wave * 32 + mt * 16 + quad * 4 + r;
      size_t rowoff = (size_t)(b * 1024 + t) * 1024 + h * 64;
#pragma unroll
      for (int nd = 0; nd < 4; nd++)
        O[rowoff + nd * 16 + l15] = f2b(o_acc[mt][nd][r] * inv);
    }
}

// ---------------- launcher ----------------
extern "C" void kernel_launch(void* const* d_in, const int* in_sizes, int n_in,
                              void* d_out, int out_size, void* d_ws, size_t ws_size,
                              hipStream_t stream)
{
  const float* x  = (const float*)d_in[0];
  const float* Wq = (const float*)d_in[1];
  const float* Wk = (const float*)d_in[2];
  const float* Wv = (const float*)d_in[3];
  const float* Wp = (const float*)d_in[4];
  float* out = (float*)d_out;
  char* ws = (char*)d_ws;
  const size_t MB = 1024 * 1024;
  // workspace map (peak 124 MB):
  u16* xh   = (u16*)(ws + 0);        // 16MB; reused as O after V-GEMM
  u16* xl   = (u16*)(ws + 16 * MB);  // 16MB
  u16* wqkh = (u16*)(ws + 32 * MB);  // 4MB  [2048][1024]
  u16* wqkl = (u16*)(ws + 36 * MB);  // 4MB
  u16* wvt  = (u16*)(ws + 40 * MB);  // 2MB
  u16* wpt  = (u16*)(ws + 42 * MB);  // 2MB
  u16* Qhf  = (u16*)(ws + 44 * MB);  // 16MB frag-major Q hi
  u16* Qlf  = (u16*)(ws + 60 * MB);  // 16MB frag-major Q lo
  u16* Khf  = (u16*)(ws + 76 * MB);  // 16MB frag-major K hi
  u16* Klf  = (u16*)(ws + 92 * MB);  // 16MB frag-major K lo
  u16* Vf   = (u16*)(ws + 108 * MB); // 16MB frag-major V
  u16* obuf = xh;
  (void)in_sizes; (void)n_in; (void)out_size; (void)ws_size;

  split_x_kernel<<<4096, 256, 0, stream>>>(x, xh, xl, 8 * 1024 * 1024);
  transpose4_kernel<<<dim3(32, 32, 4), dim3(32, 8), 0, stream>>>(
      Wq, Wk, Wv, Wp, wqkh, wqkl, wqkh + 1024 * 1024, wqkl + 1024 * 1024, wvt, wpt);
  gemm_qk_kernel<<<dim3(64, 16), 256, 0, stream>>>(xh, xl, wqkh, wqkl,
                                                   Qhf, Qlf, Khf, Klf, 8192, 2048, 1024);
  gemm_bt_kernel<2><<<dim3(64, 8), 256, 0, stream>>>(xh, wvt, (void*)Vf, 8192, 1024, 1024);
  attn_kernel<<<1024, 256, 0, stream>>>(Qhf, Qlf, Khf, Klf, Vf, obuf);
  gemm_bt_kernel<0><<<dim3(64, 8), 256, 0, stream>>>(obuf, wpt, (void*)out, 8192, 1024, 1024);
}